// Round 2
// baseline (411.213 us; speedup 1.0000x reference)
//
#include <hip/hip_runtime.h>
#include <hip/hip_bf16.h>
#include <stdint.h>

// Problem constants (B=4096, V=512, H=64)
#define BB 4096
#define VV 512
#define HH 64

typedef short bf16x8 __attribute__((ext_vector_type(8)));
typedef float floatx4 __attribute__((ext_vector_type(4)));
typedef unsigned short ushort8 __attribute__((ext_vector_type(8)));

typedef const __attribute__((address_space(1))) void g_void;
typedef __attribute__((address_space(3))) void l_void;

__device__ __forceinline__ void gload_lds16(const void* g, void* l) {
    __builtin_amdgcn_global_load_lds((g_void*)g, (l_void*)l, 16, 0, 0);
}

__device__ __forceinline__ unsigned short f2bf_rne(float f) {
    unsigned int u = __float_as_uint(f);
    u += 0x7FFFu + ((u >> 16) & 1u);   // round-to-nearest-even
    return (unsigned short)(u >> 16);
}

// ---------------------------------------------------------------- adj output
__global__ __launch_bounds__(256) void adj_kernel(const float* __restrict__ logits,
                                                  float* __restrict__ adj_out) {
    int idx = blockIdx.x * 256 + threadIdx.x;      // 0..262143
    int v = idx >> 9;
    int u = idx & (VV - 1);
    // sigmoid(x) > 0.5  <=>  x > 0 ; zero diagonal
    adj_out[idx] = (logits[idx] > 0.0f && v != u) ? 1.0f : 0.0f;
}

// ---------------------------------------------------------------- X -> bf16
__global__ __launch_bounds__(256) void x_convert_kernel(const float* __restrict__ X,
                                                        unsigned short* __restrict__ Xbf) {
    int idx = blockIdx.x * 256 + threadIdx.x;      // x4 elements
    float4 v = ((const float4*)X)[idx];
    ushort4 o;
    o.x = f2bf_rne(v.x); o.y = f2bf_rne(v.y); o.z = f2bf_rne(v.z); o.w = f2bf_rne(v.w);
    ((ushort4*)Xbf)[idx] = o;
}

// ---------------------- W1[i][v][h] * adj[v,i] -> bf16 W1t[i][h][v] (B^T layout)
__global__ __launch_bounds__(256) void w1_transform_kernel(const float* __restrict__ W1,
                                                           const float* __restrict__ logits,
                                                           unsigned short* __restrict__ W1t) {
    __shared__ float tile[64][65];   // +1 pad breaks transpose-read conflicts
    __shared__ float maskv[64];
    int bx = blockIdx.x;             // grid = 512 * 8
    int i  = bx >> 3;
    int v0 = (bx & 7) << 6;
    int t  = threadIdx.x;
    if (t < 64) {
        int v = v0 + t;
        maskv[t] = (logits[(size_t)v * VV + i] > 0.0f && v != i) ? 1.0f : 0.0f;
    }
    const float* src = W1 + ((size_t)i * VV + v0) * HH;   // 64 v-rows x 64 h, contiguous
    #pragma unroll
    for (int j = 0; j < 16; ++j) {
        int idx = j * 256 + t;
        tile[idx >> 6][idx & 63] = src[idx];
    }
    __syncthreads();
    unsigned short* dst = W1t + (size_t)i * (HH * VV) + v0;
    // 16B vector stores: 512 chunks of 8 vr, 2 per thread
    #pragma unroll
    for (int j = 0; j < 2; ++j) {
        int c = j * 256 + t;
        int h = c >> 3;
        int vr0 = (c & 7) * 8;
        ushort8 o;
        #pragma unroll
        for (int r = 0; r < 8; ++r)
            o[r] = f2bf_rne(tile[vr0 + r][h] * maskv[vr0 + r]);
        *(ushort8*)&dst[(size_t)h * VV + vr0] = o;
    }
}

// ---------------------------------------------------------------- main GEMM
// Block = (net i, 256 batch rows), 4 waves x (64 rows x 64 cols).
// W1t row i (64 KB) staged into LDS ONCE (XOR-swizzled, conflict-free reads).
// A-fragments loaded straight from global (L2-hot Xbf), ping-pong prefetched.
// K-loop has NO barriers and NO LDS writes -> no vmcnt(0) barrier drain.
__global__ __launch_bounds__(256, 2) void dag_gemm_kernel(
        const unsigned short* __restrict__ Xbf,   // [B][V] bf16
        const unsigned short* __restrict__ W1t,   // [V][H][V] bf16 (masked, B^T)
        const float* __restrict__ b1,             // [V][H]
        const float* __restrict__ W2,             // [V][H]
        const float* __restrict__ b2,             // [V]
        float* __restrict__ out)                  // [B][V]
{
    __shared__ __align__(16) unsigned short Ws[HH * VV];   // 64 KB

    const int t    = threadIdx.x;
    const int wave = t >> 6;
    const int lane = t & 63;
    const int ln   = lane & 15;
    const int quad = lane >> 4;

    const int bx   = blockIdx.x;          // 8192 blocks
    const int i    = bx & (VV - 1);       // consecutive blocks share X row-chunk (L2);
    const int row0 = (bx >> 9) << 8;      // blocks 512 apart share i (same XCD -> W1t L2)

    // ---- stage full W1t row i: 4096 chunks of 16B, swizzle sub s -> s^(h&7)
    const unsigned short* wbase = W1t + (size_t)i * (HH * VV);
    #pragma unroll
    for (int j = 0; j < 16; ++j) {
        int c = j * 256 + t;
        int h = c >> 6, s = c & 63;
        gload_lds16(wbase + (size_t)h * VV + (size_t)(s ^ (h & 7)) * 8,
                    (char*)Ws + c * 16);
    }
    __syncthreads();   // the ONLY barrier

    floatx4 acc[4][4];
    #pragma unroll
    for (int a = 0; a < 4; ++a)
        #pragma unroll
        for (int b = 0; b < 4; ++b)
            acc[a][b] = (floatx4){0.f, 0.f, 0.f, 0.f};

    // A-frag base: lane holds A[row=ln][k=quad*8..+7] == 16B row-major chunk
    const unsigned short* abase =
        Xbf + (size_t)(row0 + wave * 64 + ln) * VV + quad * 8;

    bf16x8 af[2][4], bq[2][4];
    #pragma unroll
    for (int mt = 0; mt < 4; ++mt)
        af[0][mt] = *(const bf16x8*)(abase + mt * 16 * VV);
    #pragma unroll
    for (int nt = 0; nt < 4; ++nt) {
        int h = nt * 16 + ln;
        int pos = quad ^ (ln & 7);
        bq[0][nt] = *(const bf16x8*)&Ws[h * VV + pos * 8];
    }

    #pragma unroll
    for (int kk = 0; kk < 16; ++kk) {
        const int cur = kk & 1, nxt = cur ^ 1;
        if (kk < 15) {
            const int k0 = (kk + 1) * 32;
            #pragma unroll
            for (int mt = 0; mt < 4; ++mt)
                af[nxt][mt] = *(const bf16x8*)(abase + mt * 16 * VV + k0);
            #pragma unroll
            for (int nt = 0; nt < 4; ++nt) {
                int h = nt * 16 + ln;
                int pos = (k0 / 8 + quad) ^ (ln & 7);
                bq[nxt][nt] = *(const bf16x8*)&Ws[h * VV + pos * 8];
            }
        }
        #pragma unroll
        for (int mt = 0; mt < 4; ++mt)
            #pragma unroll
            for (int nt = 0; nt < 4; ++nt)
                acc[mt][nt] = __builtin_amdgcn_mfma_f32_16x16x32_bf16(
                    af[cur][mt], bq[cur][nt], acc[mt][nt], 0, 0, 0);
    }

    // ---- fused epilogue: relu(acc + b1) . W2 + b2, fp32 throughout
    float b1v[4], w2v[4];
    #pragma unroll
    for (int nt = 0; nt < 4; ++nt) {
        b1v[nt] = b1[i * HH + nt * 16 + ln];
        w2v[nt] = W2[i * HH + nt * 16 + ln];
    }
    const float b2i = b2[i];
    #pragma unroll
    for (int mt = 0; mt < 4; ++mt) {
        #pragma unroll
        for (int r = 0; r < 4; ++r) {
            float p = 0.f;
            #pragma unroll
            for (int nt = 0; nt < 4; ++nt) {
                float hv = acc[mt][nt][r] + b1v[nt];   // C/D: row=quad*4+r, col=nt*16+ln
                hv = hv > 0.f ? hv : 0.f;
                p += hv * w2v[nt];
            }
            // sum the 16 columns held by the 16 lanes of this quad
            p += __shfl_xor(p, 8);
            p += __shfl_xor(p, 4);
            p += __shfl_xor(p, 2);
            p += __shfl_xor(p, 1);
            if (ln == 0) {
                int row = row0 + wave * 64 + mt * 16 + quad * 4 + r;
                out[(size_t)row * VV + i] = p + b2i;
            }
        }
    }
}

// ----------------------------- fallback (no workspace): fp32 vector path
__global__ __launch_bounds__(256) void fallback_kernel(
        const float* __restrict__ X, const float* __restrict__ logits,
        const float* __restrict__ W1, const float* __restrict__ b1,
        const float* __restrict__ W2, const float* __restrict__ b2,
        float* __restrict__ out) {
    __shared__ float Wc[128][64];                 // 32 KB masked W1 k-chunk
    int i   = blockIdx.x & (VV - 1);
    int row = (blockIdx.x >> 9) * 256 + threadIdx.x;
    float acc[64];
    #pragma unroll
    for (int h = 0; h < 64; ++h) acc[h] = 0.f;
    for (int v0 = 0; v0 < VV; v0 += 128) {
        __syncthreads();
        for (int j = 0; j < 32; ++j) {
            int idx = j * 256 + threadIdx.x;
            int vr = idx >> 6, h = idx & 63;
            int v = v0 + vr;
            float m = (logits[(size_t)v * VV + i] > 0.f && v != i) ? 1.f : 0.f;
            Wc[vr][h] = W1[((size_t)i * VV + v) * HH + h] * m;
        }
        __syncthreads();
        for (int vr = 0; vr < 128; ++vr) {
            float xv = X[(size_t)row * VV + v0 + vr];
            #pragma unroll
            for (int h = 0; h < 64; ++h) acc[h] += xv * Wc[vr][h];
        }
    }
    float p = b2[i];
    #pragma unroll
    for (int h = 0; h < 64; ++h) {
        float hv = acc[h] + b1[i * HH + h];
        p += (hv > 0.f ? hv : 0.f) * W2[i * HH + h];
    }
    out[(size_t)row * VV + i] = p;
}

extern "C" void kernel_launch(void* const* d_in, const int* in_sizes, int n_in,
                              void* d_out, int out_size, void* d_ws, size_t ws_size,
                              hipStream_t stream) {
    const float* X      = (const float*)d_in[0];
    const float* logits = (const float*)d_in[1];
    const float* W1     = (const float*)d_in[2];
    const float* b1     = (const float*)d_in[3];
    const float* W2     = (const float*)d_in[4];
    const float* b2     = (const float*)d_in[5];

    float* out     = (float*)d_out;                       // reconstructed [B][V]
    float* adj_out = out + (size_t)BB * VV;               // adj [V][V]

    const size_t xbf_bytes = (size_t)BB * VV * 2;         // 4 MB
    const size_t w1t_bytes = (size_t)VV * HH * VV * 2;    // 32 MB
    const size_t need = xbf_bytes + w1t_bytes;

    hipLaunchKernelGGL(adj_kernel, dim3((VV * VV) / 256), dim3(256), 0, stream,
                       logits, adj_out);

    if (ws_size >= need) {
        unsigned short* Xbf = (unsigned short*)d_ws;
        unsigned short* W1t = (unsigned short*)((char*)d_ws + xbf_bytes);
        hipLaunchKernelGGL(x_convert_kernel, dim3((BB * VV / 4) / 256), dim3(256), 0, stream,
                           X, Xbf);
        hipLaunchKernelGGL(w1_transform_kernel, dim3(VV * (VV / 64)), dim3(256), 0, stream,
                           W1, logits, W1t);
        hipLaunchKernelGGL(dag_gemm_kernel, dim3(VV * (BB / 256)), dim3(256), 0, stream,
                           Xbf, W1t, b1, W2, b2, out);
    } else {
        hipLaunchKernelGGL(fallback_kernel, dim3(VV * (BB / 256)), dim3(256), 0, stream,
                           X, logits, W1, b1, W2, b2, out);
    }
}

// Round 3
// 344.278 us; speedup vs baseline: 1.1944x; 1.1944x over previous
//
#include <hip/hip_runtime.h>
#include <hip/hip_bf16.h>
#include <stdint.h>

// Problem constants (B=4096, V=512, H=64)
#define BB 4096
#define VV 512
#define HH 64

typedef short bf16x8 __attribute__((ext_vector_type(8)));
typedef float floatx4 __attribute__((ext_vector_type(4)));
typedef unsigned short ushort8 __attribute__((ext_vector_type(8)));

typedef const __attribute__((address_space(1))) void g_void;
typedef __attribute__((address_space(3))) void l_void;

__device__ __forceinline__ void gload_lds16(const void* g, void* l) {
    __builtin_amdgcn_global_load_lds((g_void*)g, (l_void*)l, 16, 0, 0);
}

__device__ __forceinline__ unsigned short f2bf_rne(float f) {
    unsigned int u = __float_as_uint(f);
    u += 0x7FFFu + ((u >> 16) & 1u);   // round-to-nearest-even
    return (unsigned short)(u >> 16);
}

// ---------------------------------------------------------------- adj only
__global__ __launch_bounds__(256) void adj_kernel(const float* __restrict__ logits,
                                                  float* __restrict__ adj_out) {
    int idx = blockIdx.x * 256 + threadIdx.x;
    int v = idx >> 9, u = idx & (VV - 1);
    adj_out[idx] = (logits[idx] > 0.0f && v != u) ? 1.0f : 0.0f;
}

// ------------------------------------------------ adj output + X -> packed bf16
// Xp layout: [rb][ks][mt][lane][8]  (rb = row/64, ks = k/32, mt = subtile)
// lane = quad*16+ln holds X[rb*64 + mt*16 + ln][ks*32 + quad*8 .. +7]
// => every A-frag load in the GEMM is a lane-contiguous 1 KB global_load_dwordx4.
__global__ __launch_bounds__(256) void prep_kernel(const float* __restrict__ X,
                                                   const float* __restrict__ logits,
                                                   float* __restrict__ adj_out,
                                                   unsigned short* __restrict__ Xp) {
    int idx = blockIdx.x * 256 + threadIdx.x;      // [0, 262144)
    // ---- adj: sigmoid(x) > 0.5  <=>  x > 0 ; zero diagonal
    {
        int v = idx >> 9, u = idx & (VV - 1);
        adj_out[idx] = (logits[idx] > 0.0f && v != u) ? 1.0f : 0.0f;
    }
    // ---- pack chunk idx
    {
        int lane = idx & 63;
        int mt   = (idx >> 6) & 3;
        int ks   = (idx >> 8) & 15;
        int rb   = idx >> 12;
        int row  = rb * 64 + mt * 16 + (lane & 15);
        int k0   = ks * 32 + (lane >> 4) * 8;
        const float* src = X + (size_t)row * VV + k0;
        ushort8 o;
        #pragma unroll
        for (int e = 0; e < 8; ++e) o[e] = f2bf_rne(src[e]);
        *(ushort8*)(Xp + (size_t)idx * 8) = o;
    }
}

// ---------------------- W1[i][v][h] * adj[v,i] -> bf16 W1t[i][h][v] (B^T layout)
__global__ __launch_bounds__(256) void w1_transform_kernel(const float* __restrict__ W1,
                                                           const float* __restrict__ logits,
                                                           unsigned short* __restrict__ W1t) {
    __shared__ float tile[64][65];   // +1 pad breaks transpose-read conflicts
    __shared__ float maskv[64];
    int bx = blockIdx.x;             // grid = 512 * 8
    int i  = bx >> 3;
    int v0 = (bx & 7) << 6;
    int t  = threadIdx.x;
    if (t < 64) {
        int v = v0 + t;
        maskv[t] = (logits[(size_t)v * VV + i] > 0.0f && v != i) ? 1.0f : 0.0f;
    }
    const float* src = W1 + ((size_t)i * VV + v0) * HH;   // 64 v-rows x 64 h, contiguous
    #pragma unroll
    for (int j = 0; j < 16; ++j) {
        int idx = j * 256 + t;
        tile[idx >> 6][idx & 63] = src[idx];
    }
    __syncthreads();
    unsigned short* dst = W1t + (size_t)i * (HH * VV) + v0;
    #pragma unroll
    for (int j = 0; j < 2; ++j) {
        int c = j * 256 + t;
        int h = c >> 3;
        int vr0 = (c & 7) * 8;
        ushort8 o;
        #pragma unroll
        for (int r = 0; r < 8; ++r)
            o[r] = f2bf_rne(tile[vr0 + r][h] * maskv[vr0 + r]);
        *(ushort8*)&dst[(size_t)h * VV + vr0] = o;
    }
}

// ---------------------------------------------------------------- main GEMM
// Block = (net i, 256 batch rows), 4 waves x (64 rows x 64 cols).
// W1t row i (64 KB) staged into LDS ONCE (XOR-swizzled, conflict-free b128 reads).
// A-fragments: coalesced 1 KB loads from pre-packed Xp (L2-hot), ping-pong
// prefetched one K-step ahead. K-loop: NO barriers, NO LDS writes.
__global__ __launch_bounds__(256, 2) void dag_gemm_kernel(
        const unsigned short* __restrict__ Xp,    // packed A frags
        const unsigned short* __restrict__ W1t,   // [V][H][V] bf16 (masked, B^T)
        const float* __restrict__ b1,             // [V][H]
        const float* __restrict__ W2,             // [V][H]
        const float* __restrict__ b2,             // [V]
        float* __restrict__ out)                  // [B][V]
{
    __shared__ __align__(16) unsigned short Ws[HH * VV];   // 64 KB

    const int t    = threadIdx.x;
    const int wave = t >> 6;
    const int lane = t & 63;
    const int ln   = lane & 15;
    const int quad = lane >> 4;

    const int bx   = blockIdx.x;          // 8192 blocks
    const int i    = bx & (VV - 1);       // same-i blocks are 512 apart -> same XCD L2
    const int row0 = (bx >> 9) << 8;

    // ---- stage full W1t row i: 4096 chunks of 16B, swizzle sub s -> s^(h&7)
    const unsigned short* wbase = W1t + (size_t)i * (HH * VV);
    #pragma unroll
    for (int j = 0; j < 16; ++j) {
        int c = j * 256 + t;
        int h = c >> 6, s = c & 63;
        gload_lds16(wbase + (size_t)h * VV + (size_t)(s ^ (h & 7)) * 8,
                    (char*)Ws + c * 16);
    }
    __syncthreads();   // the ONLY barrier

    floatx4 acc[4][4];
    #pragma unroll
    for (int a = 0; a < 4; ++a)
        #pragma unroll
        for (int b = 0; b < 4; ++b)
            acc[a][b] = (floatx4){0.f, 0.f, 0.f, 0.f};

    // wave's packed A stream: 64 KB contiguous, frag(ks,mt) at +(ks*4+mt)*512
    const unsigned short* abase =
        Xp + (size_t)((row0 >> 6) + wave) * (64 * VV) + lane * 8;

    bf16x8 af[2][4], bq[2][4];
    #pragma unroll
    for (int mt = 0; mt < 4; ++mt)
        af[0][mt] = *(const bf16x8*)(abase + mt * 512);
    #pragma unroll
    for (int nt = 0; nt < 4; ++nt)
        bq[0][nt] = *(const bf16x8*)&Ws[(nt * 16 + ln) * VV + (quad ^ (ln & 7)) * 8];

    #pragma unroll
    for (int kk = 0; kk < 16; ++kk) {
        const int cur = kk & 1, nxt = cur ^ 1;
        if (kk < 15) {
            #pragma unroll
            for (int mt = 0; mt < 4; ++mt)
                af[nxt][mt] = *(const bf16x8*)(abase + ((kk + 1) * 4 + mt) * 512);
            #pragma unroll
            for (int nt = 0; nt < 4; ++nt)
                bq[nxt][nt] = *(const bf16x8*)
                    &Ws[(nt * 16 + ln) * VV + (((kk + 1) * 4 + quad) ^ (ln & 7)) * 8];
        }
        #pragma unroll
        for (int mt = 0; mt < 4; ++mt)
            #pragma unroll
            for (int nt = 0; nt < 4; ++nt)
                acc[mt][nt] = __builtin_amdgcn_mfma_f32_16x16x32_bf16(
                    af[cur][mt], bq[cur][nt], acc[mt][nt], 0, 0, 0);
    }

    // ---- fused epilogue: relu(acc + b1) . W2 + b2, fp32 throughout
    float b1v[4], w2v[4];
    #pragma unroll
    for (int nt = 0; nt < 4; ++nt) {
        b1v[nt] = b1[i * HH + nt * 16 + ln];
        w2v[nt] = W2[i * HH + nt * 16 + ln];
    }
    const float b2i = b2[i];
    #pragma unroll
    for (int mt = 0; mt < 4; ++mt) {
        #pragma unroll
        for (int r = 0; r < 4; ++r) {
            float p = 0.f;
            #pragma unroll
            for (int nt = 0; nt < 4; ++nt) {
                float hv = acc[mt][nt][r] + b1v[nt];   // C/D: row=quad*4+r, col=nt*16+ln
                hv = hv > 0.f ? hv : 0.f;
                p += hv * w2v[nt];
            }
            p += __shfl_xor(p, 8);
            p += __shfl_xor(p, 4);
            p += __shfl_xor(p, 2);
            p += __shfl_xor(p, 1);
            if (ln == 0) {
                int row = row0 + wave * 64 + mt * 16 + quad * 4 + r;
                out[(size_t)row * VV + i] = p + b2i;
            }
        }
    }
}

// ----------------------------- fallback (no workspace): fp32 vector path
__global__ __launch_bounds__(256) void fallback_kernel(
        const float* __restrict__ X, const float* __restrict__ logits,
        const float* __restrict__ W1, const float* __restrict__ b1,
        const float* __restrict__ W2, const float* __restrict__ b2,
        float* __restrict__ out) {
    __shared__ float Wc[128][64];                 // 32 KB masked W1 k-chunk
    int i   = blockIdx.x & (VV - 1);
    int row = (blockIdx.x >> 9) * 256 + threadIdx.x;
    float acc[64];
    #pragma unroll
    for (int h = 0; h < 64; ++h) acc[h] = 0.f;
    for (int v0 = 0; v0 < VV; v0 += 128) {
        __syncthreads();
        for (int j = 0; j < 32; ++j) {
            int idx = j * 256 + threadIdx.x;
            int vr = idx >> 6, h = idx & 63;
            int v = v0 + vr;
            float m = (logits[(size_t)v * VV + i] > 0.f && v != i) ? 1.f : 0.f;
            Wc[vr][h] = W1[((size_t)i * VV + v) * HH + h] * m;
        }
        __syncthreads();
        for (int vr = 0; vr < 128; ++vr) {
            float xv = X[(size_t)row * VV + v0 + vr];
            #pragma unroll
            for (int h = 0; h < 64; ++h) acc[h] += xv * Wc[vr][h];
        }
    }
    float p = b2[i];
    #pragma unroll
    for (int h = 0; h < 64; ++h) {
        float hv = acc[h] + b1[i * HH + h];
        p += (hv > 0.f ? hv : 0.f) * W2[i * HH + h];
    }
    out[(size_t)row * VV + i] = p;
}

extern "C" void kernel_launch(void* const* d_in, const int* in_sizes, int n_in,
                              void* d_out, int out_size, void* d_ws, size_t ws_size,
                              hipStream_t stream) {
    const float* X      = (const float*)d_in[0];
    const float* logits = (const float*)d_in[1];
    const float* W1     = (const float*)d_in[2];
    const float* b1     = (const float*)d_in[3];
    const float* W2     = (const float*)d_in[4];
    const float* b2     = (const float*)d_in[5];

    float* out     = (float*)d_out;                       // reconstructed [B][V]
    float* adj_out = out + (size_t)BB * VV;               // adj [V][V]

    const size_t xp_bytes  = (size_t)BB * VV * 2;         // 4 MB
    const size_t w1t_bytes = (size_t)VV * HH * VV * 2;    // 32 MB
    const size_t need = xp_bytes + w1t_bytes;

    if (ws_size >= need) {
        unsigned short* Xp  = (unsigned short*)d_ws;
        unsigned short* W1t = (unsigned short*)((char*)d_ws + xp_bytes);
        hipLaunchKernelGGL(prep_kernel, dim3((VV * VV) / 256), dim3(256), 0, stream,
                           X, logits, adj_out, Xp);
        hipLaunchKernelGGL(w1_transform_kernel, dim3(VV * (VV / 64)), dim3(256), 0, stream,
                           W1, logits, W1t);
        hipLaunchKernelGGL(dag_gemm_kernel, dim3(VV * (BB / 256)), dim3(256), 0, stream,
                           Xp, W1t, b1, W2, b2, out);
    } else {
        hipLaunchKernelGGL(adj_kernel, dim3((VV * VV) / 256), dim3(256), 0, stream,
                           logits, adj_out);
        hipLaunchKernelGGL(fallback_kernel, dim3(VV * (BB / 256)), dim3(256), 0, stream,
                           X, logits, W1, b1, W2, b2, out);
    }
}

// Round 4
// 280.613 us; speedup vs baseline: 1.4654x; 1.2269x over previous
//
#include <hip/hip_runtime.h>
#include <hip/hip_bf16.h>
#include <stdint.h>

// Problem constants (B=4096, V=512, H=64)
#define BB 4096
#define VV 512
#define HH 64

typedef short bf16x8 __attribute__((ext_vector_type(8)));
typedef float floatx4 __attribute__((ext_vector_type(4)));
typedef unsigned short ushort8 __attribute__((ext_vector_type(8)));

typedef const __attribute__((address_space(1))) void g_void;
typedef __attribute__((address_space(3))) void l_void;

__device__ __forceinline__ void gload_lds16(const void* g, void* l) {
    __builtin_amdgcn_global_load_lds((g_void*)g, (l_void*)l, 16, 0, 0);
}

__device__ __forceinline__ unsigned short f2bf_rne(float f) {
    unsigned int u = __float_as_uint(f);
    u += 0x7FFFu + ((u >> 16) & 1u);   // round-to-nearest-even
    return (unsigned short)(u >> 16);
}

// ---------------------------------------------------------------- adj only
__global__ __launch_bounds__(256) void adj_kernel(const float* __restrict__ logits,
                                                  float* __restrict__ adj_out) {
    int idx = blockIdx.x * 256 + threadIdx.x;
    int v = idx >> 9, u = idx & (VV - 1);
    adj_out[idx] = (logits[idx] > 0.0f && v != u) ? 1.0f : 0.0f;
}

// ------------------------------------------------ adj output + X -> packed bf16
// Xp layout: [rb][ks][mt][lane][8]  (rb = row/64, ks = k/32, mt = subtile)
// lane = quad*16+ln holds X[rb*64 + mt*16 + ln][ks*32 + quad*8 .. +7]
// => every A-frag load in the GEMM is a lane-contiguous 1 KB global_load_dwordx4.
__global__ __launch_bounds__(256) void prep_kernel(const float* __restrict__ X,
                                                   const float* __restrict__ logits,
                                                   float* __restrict__ adj_out,
                                                   unsigned short* __restrict__ Xp) {
    int idx = blockIdx.x * 256 + threadIdx.x;      // [0, 262144)
    {   // adj: sigmoid(x) > 0.5  <=>  x > 0 ; zero diagonal
        int v = idx >> 9, u = idx & (VV - 1);
        adj_out[idx] = (logits[idx] > 0.0f && v != u) ? 1.0f : 0.0f;
    }
    {   // pack chunk idx
        int lane = idx & 63;
        int mt   = (idx >> 6) & 3;
        int ks   = (idx >> 8) & 15;
        int rb   = idx >> 12;
        int row  = rb * 64 + mt * 16 + (lane & 15);
        int k0   = ks * 32 + (lane >> 4) * 8;
        const float* src = X + (size_t)row * VV + k0;
        ushort8 o;
        #pragma unroll
        for (int e = 0; e < 8; ++e) o[e] = f2bf_rne(src[e]);
        *(ushort8*)(Xp + (size_t)idx * 8) = o;
    }
}

// ---------------------- W1[i][v][h] * adj[v,i] -> bf16 W1t[i][h][v] (B^T layout)
__global__ __launch_bounds__(256) void w1_transform_kernel(const float* __restrict__ W1,
                                                           const float* __restrict__ logits,
                                                           unsigned short* __restrict__ W1t) {
    __shared__ float tile[64][65];   // +1 pad breaks transpose-read conflicts
    __shared__ float maskv[64];
    int bx = blockIdx.x;             // grid = 512 * 8
    int i  = bx >> 3;
    int v0 = (bx & 7) << 6;
    int t  = threadIdx.x;
    if (t < 64) {
        int v = v0 + t;
        maskv[t] = (logits[(size_t)v * VV + i] > 0.0f && v != i) ? 1.0f : 0.0f;
    }
    const float* src = W1 + ((size_t)i * VV + v0) * HH;   // 64 v-rows x 64 h, contiguous
    #pragma unroll
    for (int j = 0; j < 16; ++j) {
        int idx = j * 256 + t;
        tile[idx >> 6][idx & 63] = src[idx];
    }
    __syncthreads();
    unsigned short* dst = W1t + (size_t)i * (HH * VV) + v0;
    #pragma unroll
    for (int j = 0; j < 2; ++j) {
        int c = j * 256 + t;
        int h = c >> 3;
        int vr0 = (c & 7) * 8;
        ushort8 o;
        #pragma unroll
        for (int r = 0; r < 8; ++r)
            o[r] = f2bf_rne(tile[vr0 + r][h] * maskv[vr0 + r]);
        *(ushort8*)&dst[(size_t)h * VV + vr0] = o;
    }
}

// ---------------------------------------------------------------- main GEMM
// Block = (net i, 256 batch rows), 4 waves x (64 rows x 64 cols).
// i-major block order: the 16 blocks sharing W1t row i are co-resident ->
// W1t served from L2/L3, working set ~4 MB instead of 32 MB.
// W1t row i (64 KB) staged into LDS once; K-loop barrier-free; A-frags are
// coalesced 1 KB global loads from packed Xp with DEPTH-3 register prefetch.
// Epilogue gathers through LDS and writes coalesced rows to outT[V][B].
__global__ __launch_bounds__(256, 2) void dag_gemm_kernel(
        const unsigned short* __restrict__ Xp,    // packed A frags
        const unsigned short* __restrict__ W1t,   // [V][H][V] bf16 (masked, B^T)
        const float* __restrict__ b1,             // [V][H]
        const float* __restrict__ W2,             // [V][H]
        const float* __restrict__ b2,             // [V]
        float* __restrict__ outT)                 // [V][B] transposed output
{
    __shared__ __align__(16) unsigned short Ws[HH * VV];   // 64 KB
    __shared__ float Po[256];                              // epilogue gather

    const int t    = threadIdx.x;
    const int wave = t >> 6;
    const int lane = t & 63;
    const int ln   = lane & 15;
    const int quad = lane >> 4;

    const int bx   = blockIdx.x;          // 8192 blocks, i-major
    const int i    = bx >> 4;             // 16 consecutive blocks share W1t row i
    const int row0 = (bx & 15) << 8;

    // wave's packed A stream: 64 KB contiguous, frag(ks,mt) at +(ks*4+mt)*512
    const unsigned short* abase =
        Xp + (size_t)((row0 >> 6) + wave) * (64 * VV) + lane * 8;

    // ---- issue first 3 K-steps of A prefetch (oldest in vmem queue)
    bf16x8 af[4][4];
    #pragma unroll
    for (int s = 0; s < 3; ++s)
        #pragma unroll
        for (int mt = 0; mt < 4; ++mt)
            af[s][mt] = *(const bf16x8*)(abase + (s * 4 + mt) * 512);

    // ---- stage full W1t row i: 4096 chunks of 16B, swizzle sub s -> s^(h&7)
    const unsigned short* wbase = W1t + (size_t)i * (HH * VV);
    #pragma unroll
    for (int j = 0; j < 16; ++j) {
        int c = j * 256 + t;
        int h = c >> 6, s = c & 63;
        gload_lds16(wbase + (size_t)h * VV + (size_t)(s ^ (h & 7)) * 8,
                    (char*)Ws + c * 16);
    }
    __syncthreads();   // drains vmcnt: staging AND af[0..2] complete here

    floatx4 acc[4][4];
    #pragma unroll
    for (int a = 0; a < 4; ++a)
        #pragma unroll
        for (int b = 0; b < 4; ++b)
            acc[a][b] = (floatx4){0.f, 0.f, 0.f, 0.f};

    bf16x8 bq[2][4];
    #pragma unroll
    for (int nt = 0; nt < 4; ++nt)
        bq[0][nt] = *(const bf16x8*)&Ws[(nt * 16 + ln) * VV + (quad ^ (ln & 7)) * 8];

    #pragma unroll
    for (int kk = 0; kk < 16; ++kk) {
        const int cur = kk & 1, nxt = cur ^ 1;
        // A prefetch for step kk+3 into buffer (kk+3)&3 (consumed at kk-1: no WAR)
        if (kk < 13) {
            #pragma unroll
            for (int mt = 0; mt < 4; ++mt)
                af[(kk + 3) & 3][mt] =
                    *(const bf16x8*)(abase + ((kk + 3) * 4 + mt) * 512);
        }
        // B prefetch for step kk+1 (LDS, short latency)
        if (kk < 15) {
            #pragma unroll
            for (int nt = 0; nt < 4; ++nt)
                bq[nxt][nt] = *(const bf16x8*)
                    &Ws[(nt * 16 + ln) * VV + (((kk + 1) * 4 + quad) ^ (ln & 7)) * 8];
        }
        #pragma unroll
        for (int mt = 0; mt < 4; ++mt)
            #pragma unroll
            for (int nt = 0; nt < 4; ++nt)
                acc[mt][nt] = __builtin_amdgcn_mfma_f32_16x16x32_bf16(
                    af[kk & 3][mt], bq[cur][nt], acc[mt][nt], 0, 0, 0);
    }

    // ---- fused epilogue: relu(acc + b1) . W2 + b2, fp32; gather via LDS,
    //      then coalesced 256B-per-wave stores to outT[i][rows]
    float b1v[4], w2v[4];
    #pragma unroll
    for (int nt = 0; nt < 4; ++nt) {
        b1v[nt] = b1[i * HH + nt * 16 + ln];
        w2v[nt] = W2[i * HH + nt * 16 + ln];
    }
    const float b2i = b2[i];
    #pragma unroll
    for (int mt = 0; mt < 4; ++mt) {
        #pragma unroll
        for (int r = 0; r < 4; ++r) {
            float p = 0.f;
            #pragma unroll
            for (int nt = 0; nt < 4; ++nt) {
                float hv = acc[mt][nt][r] + b1v[nt];   // C/D: row=quad*4+r, col=nt*16+ln
                hv = hv > 0.f ? hv : 0.f;
                p += hv * w2v[nt];
            }
            p += __shfl_xor(p, 8);
            p += __shfl_xor(p, 4);
            p += __shfl_xor(p, 2);
            p += __shfl_xor(p, 1);
            if (ln == 0)
                Po[wave * 64 + mt * 16 + quad * 4 + r] = p + b2i;
        }
    }
    __syncthreads();
    outT[(size_t)i * BB + row0 + wave * 64 + lane] = Po[wave * 64 + lane];
}

// ------------------------------------------- outT[V][B] -> out[B][V] transpose
__global__ __launch_bounds__(256) void transpose_kernel(const float* __restrict__ outT,
                                                        float* __restrict__ out) {
    __shared__ float tile[64][65];
    int i0 = (blockIdx.x & 7) * 64;
    int r0 = (blockIdx.x >> 3) * 64;
    int t  = threadIdx.x;
    #pragma unroll
    for (int j = 0; j < 16; ++j) {
        int idx = j * 256 + t;
        int ii = idx >> 6, rr = idx & 63;
        tile[ii][rr] = outT[(size_t)(i0 + ii) * BB + r0 + rr];
    }
    __syncthreads();
    #pragma unroll
    for (int j = 0; j < 16; ++j) {
        int idx = j * 256 + t;
        int rr = idx >> 6, ii = idx & 63;
        out[(size_t)(r0 + rr) * VV + i0 + ii] = tile[ii][rr];
    }
}

// ----------------------------- fallback (no workspace): fp32 vector path
__global__ __launch_bounds__(256) void fallback_kernel(
        const float* __restrict__ X, const float* __restrict__ logits,
        const float* __restrict__ W1, const float* __restrict__ b1,
        const float* __restrict__ W2, const float* __restrict__ b2,
        float* __restrict__ out) {
    __shared__ float Wc[128][64];                 // 32 KB masked W1 k-chunk
    int i   = blockIdx.x & (VV - 1);
    int row = (blockIdx.x >> 9) * 256 + threadIdx.x;
    float acc[64];
    #pragma unroll
    for (int h = 0; h < 64; ++h) acc[h] = 0.f;
    for (int v0 = 0; v0 < VV; v0 += 128) {
        __syncthreads();
        for (int j = 0; j < 32; ++j) {
            int idx = j * 256 + threadIdx.x;
            int vr = idx >> 6, h = idx & 63;
            int v = v0 + vr;
            float m = (logits[(size_t)v * VV + i] > 0.f && v != i) ? 1.f : 0.f;
            Wc[vr][h] = W1[((size_t)i * VV + v) * HH + h] * m;
        }
        __syncthreads();
        for (int vr = 0; vr < 128; ++vr) {
            float xv = X[(size_t)row * VV + v0 + vr];
            #pragma unroll
            for (int h = 0; h < 64; ++h) acc[h] += xv * Wc[vr][h];
        }
    }
    float p = b2[i];
    #pragma unroll
    for (int h = 0; h < 64; ++h) {
        float hv = acc[h] + b1[i * HH + h];
        p += (hv > 0.f ? hv : 0.f) * W2[i * HH + h];
    }
    out[(size_t)row * VV + i] = p;
}

extern "C" void kernel_launch(void* const* d_in, const int* in_sizes, int n_in,
                              void* d_out, int out_size, void* d_ws, size_t ws_size,
                              hipStream_t stream) {
    const float* X      = (const float*)d_in[0];
    const float* logits = (const float*)d_in[1];
    const float* W1     = (const float*)d_in[2];
    const float* b1     = (const float*)d_in[3];
    const float* W2     = (const float*)d_in[4];
    const float* b2     = (const float*)d_in[5];

    float* out     = (float*)d_out;                       // reconstructed [B][V]
    float* adj_out = out + (size_t)BB * VV;               // adj [V][V]

    const size_t xp_bytes   = (size_t)BB * VV * 2;        // 4 MB
    const size_t w1t_bytes  = (size_t)VV * HH * VV * 2;   // 32 MB
    const size_t outt_bytes = (size_t)BB * VV * 4;        // 8 MB
    const size_t need = xp_bytes + w1t_bytes + outt_bytes;

    if (ws_size >= need) {
        unsigned short* Xp   = (unsigned short*)d_ws;
        unsigned short* W1t  = (unsigned short*)((char*)d_ws + xp_bytes);
        float*          outT = (float*)((char*)d_ws + xp_bytes + w1t_bytes);
        hipLaunchKernelGGL(prep_kernel, dim3((VV * VV) / 256), dim3(256), 0, stream,
                           X, logits, adj_out, Xp);
        hipLaunchKernelGGL(w1_transform_kernel, dim3(VV * (VV / 64)), dim3(256), 0, stream,
                           W1, logits, W1t);
        hipLaunchKernelGGL(dag_gemm_kernel, dim3(VV * (BB / 256)), dim3(256), 0, stream,
                           Xp, W1t, b1, W2, b2, outT);
        hipLaunchKernelGGL(transpose_kernel, dim3((BB / 64) * (VV / 64)), dim3(256), 0, stream,
                           outT, out);
    } else {
        hipLaunchKernelGGL(adj_kernel, dim3((VV * VV) / 256), dim3(256), 0, stream,
                           logits, adj_out);
        hipLaunchKernelGGL(fallback_kernel, dim3(VV * (BB / 256)), dim3(256), 0, stream,
                           X, logits, W1, b1, W2, b2, out);
    }
}